// Round 2
// baseline (741.445 us; speedup 1.0000x reference)
//
#include <hip/hip_runtime.h>
#include <math.h>

// ---------------------------------------------------------------------------
// PairwiseFeatureBatch: N=512, B=2, D=128, O=16, H=64, CH=48
//   out0: S      [512,512,2,16]  (8388608 f32)
//   out1: S_skip [511,2,16]      (16352 f32)
// ws layout (floats):
//   xc   @ 0        (513*256)
//   x2c  @ 131328
//   x3c  @ 262656
//   Sd   @ 393984   (8388608)      dense pre-conv scores
//   pk   @ 8782592  (167936 shorts) packed bf16 hi/lo weight fragments
// total ~35.4 MB
// ---------------------------------------------------------------------------

typedef __attribute__((ext_vector_type(8))) short s8v;
typedef __attribute__((ext_vector_type(4))) float f4v;

__device__ __forceinline__ unsigned short f2bf(float f){
  unsigned u = __float_as_uint(f);
  unsigned r = u + 0x7FFFu + ((u >> 16) & 1u);
  return (unsigned short)(r >> 16);
}
__device__ __forceinline__ float bf2f(unsigned short h){
  return __uint_as_float(((unsigned)h) << 16);
}
__device__ __forceinline__ float gelu_f(float v){
  return 0.5f * v * (1.0f + erff(v * 0.7071067811865476f));
}
// invert p = i*(i+1)/2 + j  (tril row-major)
__device__ __forceinline__ int inv_tri(int p){
  float t = sqrtf(8.0f * (float)p + 1.0f);
  int i = (int)((t - 1.0f) * 0.5f);
  while ((i + 1) * (i + 2) / 2 <= p) ++i;
  while (i * (i + 1) / 2 > p) --i;
  return i;
}

// ------------------------- prefix sums -------------------------------------
__global__ __launch_bounds__(256) void prefix_k(const float* __restrict__ x,
    float* __restrict__ xc, float* __restrict__ x2c, float* __restrict__ x3c)
{
  const int col = threadIdx.x;          // (b*128+d) in [0,256)
  const int mom = blockIdx.x;           // 0:x 1:x^2 2:x^3
  float* dst = (mom == 0) ? xc : ((mom == 1) ? x2c : x3c);
  float acc = 0.0f;
  dst[col] = 0.0f;
#pragma unroll 8
  for (int n = 0; n < 512; ++n){
    float v = x[n * 256 + col];
    if (mom == 1) v = v * v;
    else if (mom == 2) v = v * v * v;
    acc += v;
    dst[(n + 1) * 256 + col] = acc;
  }
}

// --------------------- pack weights into B-fragment order ------------------
// B[k][n] = W[n][k]; lane holds n = nt*16+(lane&15), k = ks*32+(lane>>4)*8+j
// pos = ((nt*KS+ks)*64+lane)*8 + j
__global__ __launch_bounds__(256) void pack_w(const float* __restrict__ W,
    int K, int KS, int nEl, short* __restrict__ hiD, short* __restrict__ loD)
{
  const int pos = blockIdx.x * 256 + threadIdx.x;
  if (pos >= nEl) return;
  const int j = pos & 7, lane = (pos >> 3) & 63, t2 = pos >> 9;
  const int ks = t2 % KS, nt = t2 / KS;
  const int n = nt * 16 + (lane & 15);
  const int k = ks * 32 + ((lane >> 4) & 3) * 8 + j;
  const float v = W[n * K + k];
  const unsigned short h = f2bf(v);
  hiD[pos] = (short)h;
  loD[pos] = (short)f2bf(v - bf2f(h));
}

// packed-area short offsets
#define W1H 0
#define W1L 49152
#define W2H 98304
#define W2L 102400
#define W3H 106496
#define W3L 107520
#define S1H 108544
#define S1L 133120
#define S2H 157696
#define S2L 161792
#define S3H 165888
#define S3L 166912

#define MFMA16 __builtin_amdgcn_mfma_f32_16x16x32_bf16

__device__ __forceinline__ void cvt_hilo(const float v[8], s8v& hi, s8v& lo){
#pragma unroll
  for (int t = 0; t < 8; ++t){
    unsigned short h = f2bf(v[t]);
    hi[t] = (short)h;
    lo[t] = (short)f2bf(v[t] - bf2f(h));
  }
}
__device__ __forceinline__ void ld8(const float* p, float v[8]){
  const float4 a0 = *(const float4*)p;
  const float4 a1 = *(const float4*)(p + 4);
  v[0]=a0.x; v[1]=a0.y; v[2]=a0.z; v[3]=a0.w;
  v[4]=a1.x; v[5]=a1.y; v[6]=a1.z; v[7]=a1.w;
}

// --------------------------- pairwise MLP ----------------------------------
// grid 1026 x 512 threads; wave handles 32 rows (2 sub-tiles of 16)
__global__ __launch_bounds__(512) void pair_mlp(
    const float* __restrict__ x, const float* __restrict__ xc,
    const float* __restrict__ x2c, const float* __restrict__ x3c,
    const short* __restrict__ pk,
    const float* __restrict__ b1, const float* __restrict__ b2,
    const float* __restrict__ b3, float* __restrict__ Sd)
{
  __shared__ __attribute__((aligned(16))) short hh[8][2048];  // [wave][32*64]
  __shared__ __attribute__((aligned(16))) short hl[8][2048];
  const int tid = threadIdx.x;
  const int wave = tid >> 6, lane = tid & 63;
  const int m = lane & 15, quad = lane >> 4;
  const int rowBase = blockIdx.x * 256 + wave * 32;

  int oi[2], oj[2], ca[2], cb[2];
  float invL[2];
#pragma unroll
  for (int s = 0; s < 2; ++s){
    const int r = rowBase + s * 16 + m;
    const int p = r >> 1, b = r & 1;
    const int i = inv_tri(p), j = p - i * (i + 1) / 2;
    oi[s] = (i * 2 + b) * 128;
    oj[s] = (j * 2 + b) * 128;
    ca[s] = (i + 1) * 256 + b * 128;
    cb[s] = j * 256 + b * 128;
    invL[s] = 1.0f / (float)(i - j + 1);
  }

  f4v acc[2][4];
#pragma unroll
  for (int s = 0; s < 2; ++s)
#pragma unroll
    for (int nt = 0; nt < 4; ++nt) acc[s][nt] = (f4v){0.f,0.f,0.f,0.f};

  // ---- layer 1: K=768, 24 k-steps ----
  for (int ks = 0; ks < 24; ++ks){
    const int chunk = ks >> 2;
    const int d0 = (ks & 3) * 32 + quad * 8;
    s8v ahi[2], alo[2];
#pragma unroll
    for (int s = 0; s < 2; ++s){
      float v[8];
      if (chunk == 0){ ld8(x + oi[s] + d0, v); }
      else if (chunk == 1){ ld8(x + oj[s] + d0, v); }
      else if (chunk == 2){
        float a[8], bb[8];
        ld8(x + oi[s] + d0, a); ld8(x + oj[s] + d0, bb);
#pragma unroll
        for (int t = 0; t < 8; ++t) v[t] = a[t] * bb[t];
      } else {
        const float* pa = (chunk == 3) ? xc : ((chunk == 4) ? x2c : x3c);
        float a[8], bb[8];
        ld8(pa + ca[s] + d0, a); ld8(pa + cb[s] + d0, bb);
#pragma unroll
        for (int t = 0; t < 8; ++t) v[t] = (a[t] - bb[t]) * invL[s];
      }
      cvt_hilo(v, ahi[s], alo[s]);
    }
#pragma unroll
    for (int nt = 0; nt < 4; ++nt){
      const int fo = ((nt * 24 + ks) * 64 + lane) << 3;
      const s8v bh = *(const s8v*)(pk + W1H + fo);
      const s8v bl = *(const s8v*)(pk + W1L + fo);
#pragma unroll
      for (int s = 0; s < 2; ++s){
        acc[s][nt] = MFMA16(ahi[s], bh, acc[s][nt], 0, 0, 0);
        acc[s][nt] = MFMA16(alo[s], bh, acc[s][nt], 0, 0, 0);
        acc[s][nt] = MFMA16(ahi[s], bl, acc[s][nt], 0, 0, 0);
      }
    }
  }
  // epilogue 1: bias + gelu -> LDS (hi/lo)
#pragma unroll
  for (int s = 0; s < 2; ++s)
#pragma unroll
    for (int nt = 0; nt < 4; ++nt){
      const float bias = b1[nt * 16 + m];
#pragma unroll
      for (int reg = 0; reg < 4; ++reg){
        float v = gelu_f(acc[s][nt][reg] + bias);
        const int idx = (s * 16 + quad * 4 + reg) * 64 + nt * 16 + m;
        unsigned short h = f2bf(v);
        hh[wave][idx] = (short)h;
        hl[wave][idx] = (short)f2bf(v - bf2f(h));
      }
    }
  __syncthreads();
  s8v a2h[2][2], a2l[2][2];
#pragma unroll
  for (int s = 0; s < 2; ++s)
#pragma unroll
    for (int k2 = 0; k2 < 2; ++k2){
      const int off = (s * 16 + m) * 64 + k2 * 32 + quad * 8;
      a2h[s][k2] = *(const s8v*)&hh[wave][off];
      a2l[s][k2] = *(const s8v*)&hl[wave][off];
    }
  __syncthreads();
  // ---- layer 2: K=64 ----
  f4v acc2[2][4];
#pragma unroll
  for (int s = 0; s < 2; ++s)
#pragma unroll
    for (int nt = 0; nt < 4; ++nt) acc2[s][nt] = (f4v){0.f,0.f,0.f,0.f};
#pragma unroll
  for (int k2 = 0; k2 < 2; ++k2)
#pragma unroll
    for (int nt = 0; nt < 4; ++nt){
      const int fo = ((nt * 2 + k2) * 64 + lane) << 3;
      const s8v bh = *(const s8v*)(pk + W2H + fo);
      const s8v bl = *(const s8v*)(pk + W2L + fo);
#pragma unroll
      for (int s = 0; s < 2; ++s){
        acc2[s][nt] = MFMA16(a2h[s][k2], bh, acc2[s][nt], 0, 0, 0);
        acc2[s][nt] = MFMA16(a2l[s][k2], bh, acc2[s][nt], 0, 0, 0);
        acc2[s][nt] = MFMA16(a2h[s][k2], bl, acc2[s][nt], 0, 0, 0);
      }
    }
#pragma unroll
  for (int s = 0; s < 2; ++s)
#pragma unroll
    for (int nt = 0; nt < 4; ++nt){
      const float bias = b2[nt * 16 + m];
#pragma unroll
      for (int reg = 0; reg < 4; ++reg){
        float v = gelu_f(acc2[s][nt][reg] + bias);
        const int idx = (s * 16 + quad * 4 + reg) * 64 + nt * 16 + m;
        unsigned short h = f2bf(v);
        hh[wave][idx] = (short)h;
        hl[wave][idx] = (short)f2bf(v - bf2f(h));
      }
    }
  __syncthreads();
  s8v a3h[2][2], a3l[2][2];
#pragma unroll
  for (int s = 0; s < 2; ++s)
#pragma unroll
    for (int k3 = 0; k3 < 2; ++k3){
      const int off = (s * 16 + m) * 64 + k3 * 32 + quad * 8;
      a3h[s][k3] = *(const s8v*)&hh[wave][off];
      a3l[s][k3] = *(const s8v*)&hl[wave][off];
    }
  // ---- layer 3: K=64, N=16 ----
  f4v acc3[2];
  acc3[0] = (f4v){0.f,0.f,0.f,0.f};
  acc3[1] = (f4v){0.f,0.f,0.f,0.f};
#pragma unroll
  for (int k3 = 0; k3 < 2; ++k3){
    const int fo = (k3 * 64 + lane) << 3;
    const s8v bh = *(const s8v*)(pk + W3H + fo);
    const s8v bl = *(const s8v*)(pk + W3L + fo);
#pragma unroll
    for (int s = 0; s < 2; ++s){
      acc3[s] = MFMA16(a3h[s][k3], bh, acc3[s], 0, 0, 0);
      acc3[s] = MFMA16(a3l[s][k3], bh, acc3[s], 0, 0, 0);
      acc3[s] = MFMA16(a3h[s][k3], bl, acc3[s], 0, 0, 0);
    }
  }
  const float bias3 = b3[m];  // o = lane&15
#pragma unroll
  for (int s = 0; s < 2; ++s)
#pragma unroll
    for (int reg = 0; reg < 4; ++reg){
      const int R = rowBase + s * 16 + quad * 4 + reg;
      const int p = R >> 1, bb = R & 1;
      const int i = inv_tri(p), j = p - i * (i + 1) / 2;
      Sd[((i * 512 + j) * 2 + bb) * 16 + m] = acc3[s][reg] + bias3;
    }
}

// ----------------------------- skip MLP ------------------------------------
// rows r = nidx*2 + b in [0,1022); grid 16 x 256 (4 waves, 16 rows each)
__global__ __launch_bounds__(256) void skip_mlp(
    const float* __restrict__ x, const short* __restrict__ pk,
    const float* __restrict__ sb1, const float* __restrict__ sb2,
    const float* __restrict__ sb3, float* __restrict__ out)
{
  __shared__ __attribute__((aligned(16))) short hh[4][1024];
  __shared__ __attribute__((aligned(16))) short hl[4][1024];
  const int tid = threadIdx.x, wave = tid >> 6, lane = tid & 63;
  const int m = lane & 15, quad = lane >> 4;
  const int rowBase = blockIdx.x * 64 + wave * 16;
  int r = rowBase + m; if (r > 1021) r = 1021;
  const int nidx = r >> 1, b = r & 1;
  const int oi = (nidx * 2 + b) * 128, oj = ((nidx + 1) * 2 + b) * 128;

  f4v acc[4];
#pragma unroll
  for (int nt = 0; nt < 4; ++nt) acc[nt] = (f4v){0.f,0.f,0.f,0.f};

  for (int ks = 0; ks < 12; ++ks){
    const int chunk = ks >> 2;
    const int d0 = (ks & 3) * 32 + quad * 8;
    float v[8];
    if (chunk == 0){ ld8(x + oi + d0, v); }
    else if (chunk == 1){ ld8(x + oj + d0, v); }
    else {
      float a[8], bb[8];
      ld8(x + oi + d0, a); ld8(x + oj + d0, bb);
#pragma unroll
      for (int t = 0; t < 8; ++t) v[t] = a[t] * bb[t];
    }
    s8v ahi, alo;
    cvt_hilo(v, ahi, alo);
#pragma unroll
    for (int nt = 0; nt < 4; ++nt){
      const int fo = ((nt * 12 + ks) * 64 + lane) << 3;
      const s8v bh = *(const s8v*)(pk + S1H + fo);
      const s8v bl = *(const s8v*)(pk + S1L + fo);
      acc[nt] = MFMA16(ahi, bh, acc[nt], 0, 0, 0);
      acc[nt] = MFMA16(alo, bh, acc[nt], 0, 0, 0);
      acc[nt] = MFMA16(ahi, bl, acc[nt], 0, 0, 0);
    }
  }
#pragma unroll
  for (int nt = 0; nt < 4; ++nt){
    const float bias = sb1[nt * 16 + m];
#pragma unroll
    for (int reg = 0; reg < 4; ++reg){
      float v = gelu_f(acc[nt][reg] + bias);
      const int idx = (quad * 4 + reg) * 64 + nt * 16 + m;
      unsigned short h = f2bf(v);
      hh[wave][idx] = (short)h;
      hl[wave][idx] = (short)f2bf(v - bf2f(h));
    }
  }
  __syncthreads();
  s8v a2h[2], a2l[2];
#pragma unroll
  for (int k2 = 0; k2 < 2; ++k2){
    const int off = m * 64 + k2 * 32 + quad * 8;
    a2h[k2] = *(const s8v*)&hh[wave][off];
    a2l[k2] = *(const s8v*)&hl[wave][off];
  }
  __syncthreads();
  f4v acc2[4];
#pragma unroll
  for (int nt = 0; nt < 4; ++nt) acc2[nt] = (f4v){0.f,0.f,0.f,0.f};
#pragma unroll
  for (int k2 = 0; k2 < 2; ++k2)
#pragma unroll
    for (int nt = 0; nt < 4; ++nt){
      const int fo = ((nt * 2 + k2) * 64 + lane) << 3;
      const s8v bh = *(const s8v*)(pk + S2H + fo);
      const s8v bl = *(const s8v*)(pk + S2L + fo);
      acc2[nt] = MFMA16(a2h[k2], bh, acc2[nt], 0, 0, 0);
      acc2[nt] = MFMA16(a2l[k2], bh, acc2[nt], 0, 0, 0);
      acc2[nt] = MFMA16(a2h[k2], bl, acc2[nt], 0, 0, 0);
    }
#pragma unroll
  for (int nt = 0; nt < 4; ++nt){
    const float bias = sb2[nt * 16 + m];
#pragma unroll
    for (int reg = 0; reg < 4; ++reg){
      float v = gelu_f(acc2[nt][reg] + bias);
      const int idx = (quad * 4 + reg) * 64 + nt * 16 + m;
      unsigned short h = f2bf(v);
      hh[wave][idx] = (short)h;
      hl[wave][idx] = (short)f2bf(v - bf2f(h));
    }
  }
  __syncthreads();
  s8v a3h[2], a3l[2];
#pragma unroll
  for (int k3 = 0; k3 < 2; ++k3){
    const int off = m * 64 + k3 * 32 + quad * 8;
    a3h[k3] = *(const s8v*)&hh[wave][off];
    a3l[k3] = *(const s8v*)&hl[wave][off];
  }
  f4v acc3 = (f4v){0.f,0.f,0.f,0.f};
#pragma unroll
  for (int k3 = 0; k3 < 2; ++k3){
    const int fo = (k3 * 64 + lane) << 3;
    const s8v bh = *(const s8v*)(pk + S3H + fo);
    const s8v bl = *(const s8v*)(pk + S3L + fo);
    acc3 = MFMA16(a3h[k3], bh, acc3, 0, 0, 0);
    acc3 = MFMA16(a3l[k3], bh, acc3, 0, 0, 0);
    acc3 = MFMA16(a3h[k3], bl, acc3, 0, 0, 0);
  }
  const float bias3 = sb3[m];
#pragma unroll
  for (int reg = 0; reg < 4; ++reg){
    const int R = rowBase + quad * 4 + reg;
    if (R < 1022) out[R * 16 + m] = acc3[reg] + bias3;
  }
}

// --------------------- fused conv1(pad2)+gelu+conv2+len --------------------
// block: 16x16 out tile for one b; oc-chunks of 12 (4 passes); f32 exact.
__global__ __launch_bounds__(256) void conv_fused(
    const float* __restrict__ Sd, const float* __restrict__ cw1,
    const float* __restrict__ cb1, const float* __restrict__ cw2,
    const float* __restrict__ cb2, float* __restrict__ out)
{
  __shared__ __attribute__((aligned(16))) float sT[16 * 400];   // [ic][20][20]
  __shared__ __attribute__((aligned(16))) float hT[12 * 360];   // [ocl][18][20]
  __shared__ __attribute__((aligned(16))) float w1T[16 * 9 * 12]; // [ic][tap][ocl]
  __shared__ __attribute__((aligned(16))) float w2T[12 * 9 * 16]; // [cl][tap][oc]
  __shared__ float cb1s[48];
  __shared__ float cb2s[16];
  const int tid = threadIdx.x;
  const int X0 = blockIdx.x * 16, Y0 = blockIdx.y * 16, bb = blockIdx.z;

  // stage S tile (zero-padded halo of 2)
  for (int e4 = tid; e4 < 1600; e4 += 256){
    const int q = e4 & 3, pix = e4 >> 2;
    const int row = pix / 20, col = pix % 20;
    const int gy = Y0 - 2 + row, gx = X0 - 2 + col;
    float4 v = make_float4(0.f, 0.f, 0.f, 0.f);
    if (gy >= 0 && gy < 512 && gx >= 0 && gx < 512)
      v = *(const float4*)(Sd + (((gy * 512 + gx) * 2 + bb) * 16 + q * 4));
    const int base = row * 20 + col;
    sT[(q * 4 + 0) * 400 + base] = v.x;
    sT[(q * 4 + 1) * 400 + base] = v.y;
    sT[(q * 4 + 2) * 400 + base] = v.z;
    sT[(q * 4 + 3) * 400 + base] = v.w;
  }
  if (tid < 48) cb1s[tid] = cb1[tid];
  if (tid < 16) cb2s[tid] = cb2[tid];
  __syncthreads();

  // conv2 thread tile: 2(Y) x 2(X) x 4(oc); 8*8*4 = 256 tiles exactly.
  // (round-1 bug: 4x2x4 with ty in 0..7 wrote Y0+16..31 — OOB stomp.)
  const int ty = tid >> 5, rm = tid & 31, tx2 = rm >> 2, ot2 = rm & 3;
  const int y0 = ty * 2, xx0 = tx2 * 2, ocB2 = ot2 * 4;
  float a2[2][2][4];
#pragma unroll
  for (int dy = 0; dy < 2; ++dy)
#pragma unroll
    for (int dx = 0; dx < 2; ++dx)
#pragma unroll
      for (int o = 0; o < 4; ++o) a2[dy][dx][o] = cb2s[ocB2 + o];

  // conv1 thread tile: 3(u) x 3(v) x 2(oc); 216 active threads
  const bool c1act = (tid < 216);
  int ut = 0, vt = 0, ot1 = 0;
  if (c1act){ ut = tid / 36; const int rr = tid % 36; vt = rr / 6; ot1 = rr % 6; }
  const int u0 = ut * 3, v0 = vt * 3, ocB1 = ot1 * 2;

  for (int ch = 0; ch < 4; ++ch){
    for (int e = tid; e < 1728; e += 256){
      const int ic = e / 108, rr = e % 108, tap = rr / 12, ocl = rr % 12;
      w1T[(ic * 9 + tap) * 12 + ocl] = cw1[(((ch * 12 + ocl) * 16 + ic) * 9 + tap)];
    }
    for (int e = tid; e < 1728; e += 256){
      const int cl = e / 144, rr = e % 144, tap = rr / 16, oc = rr % 16;
      w2T[(cl * 9 + tap) * 16 + oc] = cw2[((oc * 48 + ch * 12 + cl) * 9 + tap)];
    }
    __syncthreads();
    // conv1: h[ocl][u][v] over this chunk
    if (c1act){
      float a1[3][3][2];
#pragma unroll
      for (int du = 0; du < 3; ++du)
#pragma unroll
        for (int dv = 0; dv < 3; ++dv){
          a1[du][dv][0] = cb1s[ch * 12 + ocB1 + 0];
          a1[du][dv][1] = cb1s[ch * 12 + ocB1 + 1];
        }
      for (int ic = 0; ic < 16; ++ic){
        float sv[5][5];
#pragma unroll
        for (int rr2 = 0; rr2 < 5; ++rr2)
#pragma unroll
          for (int cc = 0; cc < 5; ++cc)
            sv[rr2][cc] = sT[ic * 400 + (u0 + rr2) * 20 + (v0 + cc)];
#pragma unroll
        for (int tap = 0; tap < 9; ++tap){
          const int ky = tap / 3, kx = tap % 3;
          const float2 wv = *(const float2*)&w1T[(ic * 9 + tap) * 12 + ocB1];
#pragma unroll
          for (int du = 0; du < 3; ++du)
#pragma unroll
            for (int dv = 0; dv < 3; ++dv){
              const float s = sv[du + ky][dv + kx];
              a1[du][dv][0] += s * wv.x;
              a1[du][dv][1] += s * wv.y;
            }
        }
      }
#pragma unroll
      for (int du = 0; du < 3; ++du)
#pragma unroll
        for (int dv = 0; dv < 3; ++dv){
          hT[(ocB1 + 0) * 360 + (u0 + du) * 20 + (v0 + dv)] = gelu_f(a1[du][dv][0]);
          hT[(ocB1 + 1) * 360 + (u0 + du) * 20 + (v0 + dv)] = gelu_f(a1[du][dv][1]);
        }
    }
    __syncthreads();
    // conv2 partial accumulation over this chunk's 12 channels
    for (int cl = 0; cl < 12; ++cl){
      float hp[4][4];
#pragma unroll
      for (int rr2 = 0; rr2 < 4; ++rr2){
        const float2 h0 = *(const float2*)&hT[cl * 360 + (y0 + rr2) * 20 + xx0];
        const float2 h1 = *(const float2*)&hT[cl * 360 + (y0 + rr2) * 20 + xx0 + 2];
        hp[rr2][0] = h0.x; hp[rr2][1] = h0.y; hp[rr2][2] = h1.x; hp[rr2][3] = h1.y;
      }
#pragma unroll
      for (int tap = 0; tap < 9; ++tap){
        const int cy = tap / 3, cx = tap % 3;
        const float4 wv = *(const float4*)&w2T[(cl * 9 + tap) * 16 + ocB2];
#pragma unroll
        for (int dy = 0; dy < 2; ++dy)
#pragma unroll
          for (int dx = 0; dx < 2; ++dx){
            const float hv = hp[dy + cy][dx + cx];
            a2[dy][dx][0] += hv * wv.x;
            a2[dy][dx][1] += hv * wv.y;
            a2[dy][dx][2] += hv * wv.z;
            a2[dy][dx][3] += hv * wv.w;
          }
      }
    }
    __syncthreads();
  }
  // scale by lenBA and store
#pragma unroll
  for (int dy = 0; dy < 2; ++dy)
#pragma unroll
    for (int dx = 0; dx < 2; ++dx){
      const int Y = Y0 + y0 + dy, X = X0 + xx0 + dx;
      int l = Y - X; if (l < 0) l = -l; if (l < 1) l = 1;
      const float lf = (float)l;
      float4 o4 = make_float4(a2[dy][dx][0] * lf, a2[dy][dx][1] * lf,
                              a2[dy][dx][2] * lf, a2[dy][dx][3] * lf);
      *(float4*)(out + (((Y * 512 + X) * 2 + bb) * 16 + ocB2)) = o4;
    }
}

// ---------------------------------------------------------------------------
extern "C" void kernel_launch(void* const* d_in, const int* in_sizes, int n_in,
                              void* d_out, int out_size, void* d_ws, size_t ws_size,
                              hipStream_t stream)
{
  (void)in_sizes; (void)n_in; (void)out_size; (void)ws_size;
  const float* x   = (const float*)d_in[0];
  const float* w1  = (const float*)d_in[1];
  const float* b1  = (const float*)d_in[2];
  const float* w2  = (const float*)d_in[3];
  const float* b2  = (const float*)d_in[4];
  const float* w3  = (const float*)d_in[5];
  const float* b3  = (const float*)d_in[6];
  const float* sw1 = (const float*)d_in[7];
  const float* sb1 = (const float*)d_in[8];
  const float* sw2 = (const float*)d_in[9];
  const float* sb2 = (const float*)d_in[10];
  const float* sw3 = (const float*)d_in[11];
  const float* sb3 = (const float*)d_in[12];
  const float* cw1 = (const float*)d_in[13];
  const float* cb1 = (const float*)d_in[14];
  const float* cw2 = (const float*)d_in[15];
  const float* cb2 = (const float*)d_in[16];

  float* ws  = (float*)d_ws;
  float* xc  = ws;
  float* x2c = ws + 131328;
  float* x3c = ws + 262656;
  float* Sd  = ws + 393984;
  short* pk  = (short*)(ws + 8782592);
  float* outS = (float*)d_out;
  float* outK = outS + 8388608;

  prefix_k<<<3, 256, 0, stream>>>(x, xc, x2c, x3c);
  pack_w<<<192, 256, 0, stream>>>(w1, 768, 24, 49152, pk + W1H, pk + W1L);
  pack_w<<<16,  256, 0, stream>>>(w2,  64,  2,  4096, pk + W2H, pk + W2L);
  pack_w<<<4,   256, 0, stream>>>(w3,  64,  2,  1024, pk + W3H, pk + W3L);
  pack_w<<<96,  256, 0, stream>>>(sw1, 384, 12, 24576, pk + S1H, pk + S1L);
  pack_w<<<16,  256, 0, stream>>>(sw2, 64,  2,  4096, pk + S2H, pk + S2L);
  pack_w<<<4,   256, 0, stream>>>(sw3, 64,  2,  1024, pk + S3H, pk + S3L);
  hipMemsetAsync(Sd, 0, (size_t)8388608 * 4, stream);
  pair_mlp<<<1026, 512, 0, stream>>>(x, xc, x2c, x3c, pk, b1, b2, b3, Sd);
  skip_mlp<<<16, 256, 0, stream>>>(x, pk, sb1, sb2, sb3, outK);
  conv_fused<<<dim3(32, 32, 2), 256, 0, stream>>>(Sd, cw1, cb1, cw2, cb2, outS);
}

// Round 3
// 591.636 us; speedup vs baseline: 1.2532x; 1.2532x over previous
//
#include <hip/hip_runtime.h>
#include <math.h>

// ---------------------------------------------------------------------------
// PairwiseFeatureBatch: N=512, B=2, D=128, O=16, H=64, CH=48
//   out0: S      [512,512,2,16]  (8388608 f32)
//   out1: S_skip [511,2,16]      (16352 f32)
// ws layout (floats):
//   xc   @ 0        (513*256)
//   x2c  @ 131328
//   x3c  @ 262656
//   Sd   @ 393984   (8388608)      dense pre-conv scores
//   pk   @ 8782592  (198656 shorts) packed bf16 hi/lo weight fragments
// ---------------------------------------------------------------------------

typedef __attribute__((ext_vector_type(8))) short s8v;
typedef __attribute__((ext_vector_type(4))) short s4v;
typedef __attribute__((ext_vector_type(4))) float f4v;

__device__ __forceinline__ unsigned short f2bf(float f){
  unsigned u = __float_as_uint(f);
  unsigned r = u + 0x7FFFu + ((u >> 16) & 1u);
  return (unsigned short)(r >> 16);
}
__device__ __forceinline__ float bf2f(unsigned short h){
  return __uint_as_float(((unsigned)h) << 16);
}
__device__ __forceinline__ float gelu_f(float v){
  return 0.5f * v * (1.0f + erff(v * 0.7071067811865476f));
}
// invert p = i*(i+1)/2 + j  (tril row-major)
__device__ __forceinline__ int inv_tri(int p){
  float t = sqrtf(8.0f * (float)p + 1.0f);
  int i = (int)((t - 1.0f) * 0.5f);
  while ((i + 1) * (i + 2) / 2 <= p) ++i;
  while (i * (i + 1) / 2 > p) --i;
  return i;
}

// ------------------------- prefix sums -------------------------------------
__global__ __launch_bounds__(256) void prefix_k(const float* __restrict__ x,
    float* __restrict__ xc, float* __restrict__ x2c, float* __restrict__ x3c)
{
  const int col = threadIdx.x;
  const int mom = blockIdx.x;
  float* dst = (mom == 0) ? xc : ((mom == 1) ? x2c : x3c);
  float acc = 0.0f;
  dst[col] = 0.0f;
#pragma unroll 8
  for (int n = 0; n < 512; ++n){
    float v = x[n * 256 + col];
    if (mom == 1) v = v * v;
    else if (mom == 2) v = v * v * v;
    acc += v;
    dst[(n + 1) * 256 + col] = acc;
  }
}

// --------------------- pack weights into B-fragment order ------------------
// B[k][n] = W[n][k]; lane holds n = nt*16+(lane&15), k = ks*32+(lane>>4)*8+j
__global__ __launch_bounds__(256) void pack_w(const float* __restrict__ W,
    int K, int KS, int nEl, short* __restrict__ hiD, short* __restrict__ loD)
{
  const int pos = blockIdx.x * 256 + threadIdx.x;
  if (pos >= nEl) return;
  const int j = pos & 7, lane = (pos >> 3) & 63, t2 = pos >> 9;
  const int ks = t2 % KS, nt = t2 / KS;
  const int n = nt * 16 + (lane & 15);
  const int k = ks * 32 + ((lane >> 4) & 3) * 8 + j;
  const float v = W[n * K + k];
  const unsigned short h = f2bf(v);
  hiD[pos] = (short)h;
  loD[pos] = (short)f2bf(v - bf2f(h));
}

// conv weight packs: K-order = tap-major(16 per tap), padded to 10 taps (K=160)
// conv1: n = oc (3 chunks of 16), k = tap*16 + ic(16)
__global__ __launch_bounds__(256) void pack_c1(const float* __restrict__ W,
    short* __restrict__ hiD, short* __restrict__ loD)
{
  const int pos = blockIdx.x * 256 + threadIdx.x;   // 7680
  const int j = pos & 7, lane = (pos >> 3) & 63, t2 = pos >> 9; // t2 = chunk*5+ks
  const int ks = t2 % 5, chunk = t2 / 5;
  const int n = chunk * 16 + (lane & 15);
  const int k = ks * 32 + ((lane >> 4) & 3) * 8 + j;
  const int tap = k >> 4, ic = k & 15;
  const float v = (tap < 9) ? W[(n * 16 + ic) * 9 + tap] : 0.0f;
  const unsigned short h = f2bf(v);
  hiD[pos] = (short)h;
  loD[pos] = (short)f2bf(v - bf2f(h));
}
// conv2: n = oc(16), k = tap*16 + icl, ic = chunk*16+icl (3 chunks)
__global__ __launch_bounds__(256) void pack_c2(const float* __restrict__ W,
    short* __restrict__ hiD, short* __restrict__ loD)
{
  const int pos = blockIdx.x * 256 + threadIdx.x;   // 7680
  const int j = pos & 7, lane = (pos >> 3) & 63, t2 = pos >> 9;
  const int ks = t2 % 5, chunk = t2 / 5;
  const int n = lane & 15;
  const int k = ks * 32 + ((lane >> 4) & 3) * 8 + j;
  const int tap = k >> 4, ic = chunk * 16 + (k & 15);
  const float v = (tap < 9) ? W[(n * 48 + ic) * 9 + tap] : 0.0f;
  const unsigned short h = f2bf(v);
  hiD[pos] = (short)h;
  loD[pos] = (short)f2bf(v - bf2f(h));
}

// packed-area short offsets
#define W1H 0
#define W1L 49152
#define W2H 98304
#define W2L 102400
#define W3H 106496
#define W3L 107520
#define S1H 108544
#define S1L 133120
#define S2H 157696
#define S2L 161792
#define S3H 165888
#define S3L 166912
#define C1H 167936
#define C1L 175616
#define C2H 183296
#define C2L 190976
// end 198656 shorts

#define MFMA16 __builtin_amdgcn_mfma_f32_16x16x32_bf16

__device__ __forceinline__ void cvt_hilo(const float v[8], s8v& hi, s8v& lo){
#pragma unroll
  for (int t = 0; t < 8; ++t){
    unsigned short h = f2bf(v[t]);
    hi[t] = (short)h;
    lo[t] = (short)f2bf(v[t] - bf2f(h));
  }
}
__device__ __forceinline__ void ld8(const float* p, float v[8]){
  const float4 a0 = *(const float4*)p;
  const float4 a1 = *(const float4*)(p + 4);
  v[0]=a0.x; v[1]=a0.y; v[2]=a0.z; v[3]=a0.w;
  v[4]=a1.x; v[5]=a1.y; v[6]=a1.z; v[7]=a1.w;
}

// --------------------------- pairwise MLP ----------------------------------
__global__ __launch_bounds__(512) void pair_mlp(
    const float* __restrict__ x, const float* __restrict__ xc,
    const float* __restrict__ x2c, const float* __restrict__ x3c,
    const short* __restrict__ pk,
    const float* __restrict__ b1, const float* __restrict__ b2,
    const float* __restrict__ b3, float* __restrict__ Sd)
{
  __shared__ __attribute__((aligned(16))) short hh[8][2048];
  __shared__ __attribute__((aligned(16))) short hl[8][2048];
  const int tid = threadIdx.x;
  const int wave = tid >> 6, lane = tid & 63;
  const int m = lane & 15, quad = lane >> 4;
  const int rowBase = blockIdx.x * 256 + wave * 32;

  int oi[2], oj[2], ca[2], cb[2];
  float invL[2];
#pragma unroll
  for (int s = 0; s < 2; ++s){
    const int r = rowBase + s * 16 + m;
    const int p = r >> 1, b = r & 1;
    const int i = inv_tri(p), j = p - i * (i + 1) / 2;
    oi[s] = (i * 2 + b) * 128;
    oj[s] = (j * 2 + b) * 128;
    ca[s] = (i + 1) * 256 + b * 128;
    cb[s] = j * 256 + b * 128;
    invL[s] = 1.0f / (float)(i - j + 1);
  }

  f4v acc[2][4];
#pragma unroll
  for (int s = 0; s < 2; ++s)
#pragma unroll
    for (int nt = 0; nt < 4; ++nt) acc[s][nt] = (f4v){0.f,0.f,0.f,0.f};

  for (int ks = 0; ks < 24; ++ks){
    const int chunk = ks >> 2;
    const int d0 = (ks & 3) * 32 + quad * 8;
    s8v ahi[2], alo[2];
#pragma unroll
    for (int s = 0; s < 2; ++s){
      float v[8];
      if (chunk == 0){ ld8(x + oi[s] + d0, v); }
      else if (chunk == 1){ ld8(x + oj[s] + d0, v); }
      else if (chunk == 2){
        float a[8], bb[8];
        ld8(x + oi[s] + d0, a); ld8(x + oj[s] + d0, bb);
#pragma unroll
        for (int t = 0; t < 8; ++t) v[t] = a[t] * bb[t];
      } else {
        const float* pa = (chunk == 3) ? xc : ((chunk == 4) ? x2c : x3c);
        float a[8], bb[8];
        ld8(pa + ca[s] + d0, a); ld8(pa + cb[s] + d0, bb);
#pragma unroll
        for (int t = 0; t < 8; ++t) v[t] = (a[t] - bb[t]) * invL[s];
      }
      cvt_hilo(v, ahi[s], alo[s]);
    }
#pragma unroll
    for (int nt = 0; nt < 4; ++nt){
      const int fo = ((nt * 24 + ks) * 64 + lane) << 3;
      const s8v bh = *(const s8v*)(pk + W1H + fo);
      const s8v bl = *(const s8v*)(pk + W1L + fo);
#pragma unroll
      for (int s = 0; s < 2; ++s){
        acc[s][nt] = MFMA16(ahi[s], bh, acc[s][nt], 0, 0, 0);
        acc[s][nt] = MFMA16(alo[s], bh, acc[s][nt], 0, 0, 0);
        acc[s][nt] = MFMA16(ahi[s], bl, acc[s][nt], 0, 0, 0);
      }
    }
  }
#pragma unroll
  for (int s = 0; s < 2; ++s)
#pragma unroll
    for (int nt = 0; nt < 4; ++nt){
      const float bias = b1[nt * 16 + m];
#pragma unroll
      for (int reg = 0; reg < 4; ++reg){
        float v = gelu_f(acc[s][nt][reg] + bias);
        const int idx = (s * 16 + quad * 4 + reg) * 64 + nt * 16 + m;
        unsigned short h = f2bf(v);
        hh[wave][idx] = (short)h;
        hl[wave][idx] = (short)f2bf(v - bf2f(h));
      }
    }
  __syncthreads();
  s8v a2h[2][2], a2l[2][2];
#pragma unroll
  for (int s = 0; s < 2; ++s)
#pragma unroll
    for (int k2 = 0; k2 < 2; ++k2){
      const int off = (s * 16 + m) * 64 + k2 * 32 + quad * 8;
      a2h[s][k2] = *(const s8v*)&hh[wave][off];
      a2l[s][k2] = *(const s8v*)&hl[wave][off];
    }
  __syncthreads();
  f4v acc2[2][4];
#pragma unroll
  for (int s = 0; s < 2; ++s)
#pragma unroll
    for (int nt = 0; nt < 4; ++nt) acc2[s][nt] = (f4v){0.f,0.f,0.f,0.f};
#pragma unroll
  for (int k2 = 0; k2 < 2; ++k2)
#pragma unroll
    for (int nt = 0; nt < 4; ++nt){
      const int fo = ((nt * 2 + k2) * 64 + lane) << 3;
      const s8v bh = *(const s8v*)(pk + W2H + fo);
      const s8v bl = *(const s8v*)(pk + W2L + fo);
#pragma unroll
      for (int s = 0; s < 2; ++s){
        acc2[s][nt] = MFMA16(a2h[s][k2], bh, acc2[s][nt], 0, 0, 0);
        acc2[s][nt] = MFMA16(a2l[s][k2], bh, acc2[s][nt], 0, 0, 0);
        acc2[s][nt] = MFMA16(a2h[s][k2], bl, acc2[s][nt], 0, 0, 0);
      }
    }
#pragma unroll
  for (int s = 0; s < 2; ++s)
#pragma unroll
    for (int nt = 0; nt < 4; ++nt){
      const float bias = b2[nt * 16 + m];
#pragma unroll
      for (int reg = 0; reg < 4; ++reg){
        float v = gelu_f(acc2[s][nt][reg] + bias);
        const int idx = (s * 16 + quad * 4 + reg) * 64 + nt * 16 + m;
        unsigned short h = f2bf(v);
        hh[wave][idx] = (short)h;
        hl[wave][idx] = (short)f2bf(v - bf2f(h));
      }
    }
  __syncthreads();
  s8v a3h[2][2], a3l[2][2];
#pragma unroll
  for (int s = 0; s < 2; ++s)
#pragma unroll
    for (int k3 = 0; k3 < 2; ++k3){
      const int off = (s * 16 + m) * 64 + k3 * 32 + quad * 8;
      a3h[s][k3] = *(const s8v*)&hh[wave][off];
      a3l[s][k3] = *(const s8v*)&hl[wave][off];
    }
  f4v acc3[2];
  acc3[0] = (f4v){0.f,0.f,0.f,0.f};
  acc3[1] = (f4v){0.f,0.f,0.f,0.f};
#pragma unroll
  for (int k3 = 0; k3 < 2; ++k3){
    const int fo = (k3 * 64 + lane) << 3;
    const s8v bh = *(const s8v*)(pk + W3H + fo);
    const s8v bl = *(const s8v*)(pk + W3L + fo);
#pragma unroll
    for (int s = 0; s < 2; ++s){
      acc3[s] = MFMA16(a3h[s][k3], bh, acc3[s], 0, 0, 0);
      acc3[s] = MFMA16(a3l[s][k3], bh, acc3[s], 0, 0, 0);
      acc3[s] = MFMA16(a3h[s][k3], bl, acc3[s], 0, 0, 0);
    }
  }
  const float bias3 = b3[m];
#pragma unroll
  for (int s = 0; s < 2; ++s)
#pragma unroll
    for (int reg = 0; reg < 4; ++reg){
      const int R = rowBase + s * 16 + quad * 4 + reg;
      const int p = R >> 1, bb = R & 1;
      const int i = inv_tri(p), j = p - i * (i + 1) / 2;
      Sd[((i * 512 + j) * 2 + bb) * 16 + m] = acc3[s][reg] + bias3;
    }
}

// ----------------------------- skip MLP ------------------------------------
__global__ __launch_bounds__(256) void skip_mlp(
    const float* __restrict__ x, const short* __restrict__ pk,
    const float* __restrict__ sb1, const float* __restrict__ sb2,
    const float* __restrict__ sb3, float* __restrict__ out)
{
  __shared__ __attribute__((aligned(16))) short hh[4][1024];
  __shared__ __attribute__((aligned(16))) short hl[4][1024];
  const int tid = threadIdx.x, wave = tid >> 6, lane = tid & 63;
  const int m = lane & 15, quad = lane >> 4;
  const int rowBase = blockIdx.x * 64 + wave * 16;
  int r = rowBase + m; if (r > 1021) r = 1021;
  const int nidx = r >> 1, b = r & 1;
  const int oi = (nidx * 2 + b) * 128, oj = ((nidx + 1) * 2 + b) * 128;

  f4v acc[4];
#pragma unroll
  for (int nt = 0; nt < 4; ++nt) acc[nt] = (f4v){0.f,0.f,0.f,0.f};

  for (int ks = 0; ks < 12; ++ks){
    const int chunk = ks >> 2;
    const int d0 = (ks & 3) * 32 + quad * 8;
    float v[8];
    if (chunk == 0){ ld8(x + oi + d0, v); }
    else if (chunk == 1){ ld8(x + oj + d0, v); }
    else {
      float a[8], bb[8];
      ld8(x + oi + d0, a); ld8(x + oj + d0, bb);
#pragma unroll
      for (int t = 0; t < 8; ++t) v[t] = a[t] * bb[t];
    }
    s8v ahi, alo;
    cvt_hilo(v, ahi, alo);
#pragma unroll
    for (int nt = 0; nt < 4; ++nt){
      const int fo = ((nt * 12 + ks) * 64 + lane) << 3;
      const s8v bh = *(const s8v*)(pk + S1H + fo);
      const s8v bl = *(const s8v*)(pk + S1L + fo);
      acc[nt] = MFMA16(ahi, bh, acc[nt], 0, 0, 0);
      acc[nt] = MFMA16(alo, bh, acc[nt], 0, 0, 0);
      acc[nt] = MFMA16(ahi, bl, acc[nt], 0, 0, 0);
    }
  }
#pragma unroll
  for (int nt = 0; nt < 4; ++nt){
    const float bias = sb1[nt * 16 + m];
#pragma unroll
    for (int reg = 0; reg < 4; ++reg){
      float v = gelu_f(acc[nt][reg] + bias);
      const int idx = (quad * 4 + reg) * 64 + nt * 16 + m;
      unsigned short h = f2bf(v);
      hh[wave][idx] = (short)h;
      hl[wave][idx] = (short)f2bf(v - bf2f(h));
    }
  }
  __syncthreads();
  s8v a2h[2], a2l[2];
#pragma unroll
  for (int k2 = 0; k2 < 2; ++k2){
    const int off = m * 64 + k2 * 32 + quad * 8;
    a2h[k2] = *(const s8v*)&hh[wave][off];
    a2l[k2] = *(const s8v*)&hl[wave][off];
  }
  __syncthreads();
  f4v acc2[4];
#pragma unroll
  for (int nt = 0; nt < 4; ++nt) acc2[nt] = (f4v){0.f,0.f,0.f,0.f};
#pragma unroll
  for (int k2 = 0; k2 < 2; ++k2)
#pragma unroll
    for (int nt = 0; nt < 4; ++nt){
      const int fo = ((nt * 2 + k2) * 64 + lane) << 3;
      const s8v bh = *(const s8v*)(pk + S2H + fo);
      const s8v bl = *(const s8v*)(pk + S2L + fo);
      acc2[nt] = MFMA16(a2h[k2], bh, acc2[nt], 0, 0, 0);
      acc2[nt] = MFMA16(a2l[k2], bh, acc2[nt], 0, 0, 0);
      acc2[nt] = MFMA16(a2h[k2], bl, acc2[nt], 0, 0, 0);
    }
#pragma unroll
  for (int nt = 0; nt < 4; ++nt){
    const float bias = sb2[nt * 16 + m];
#pragma unroll
    for (int reg = 0; reg < 4; ++reg){
      float v = gelu_f(acc2[nt][reg] + bias);
      const int idx = (quad * 4 + reg) * 64 + nt * 16 + m;
      unsigned short h = f2bf(v);
      hh[wave][idx] = (short)h;
      hl[wave][idx] = (short)f2bf(v - bf2f(h));
    }
  }
  __syncthreads();
  s8v a3h[2], a3l[2];
#pragma unroll
  for (int k3 = 0; k3 < 2; ++k3){
    const int off = m * 64 + k3 * 32 + quad * 8;
    a3h[k3] = *(const s8v*)&hh[wave][off];
    a3l[k3] = *(const s8v*)&hl[wave][off];
  }
  f4v acc3 = (f4v){0.f,0.f,0.f,0.f};
#pragma unroll
  for (int k3 = 0; k3 < 2; ++k3){
    const int fo = (k3 * 64 + lane) << 3;
    const s8v bh = *(const s8v*)(pk + S3H + fo);
    const s8v bl = *(const s8v*)(pk + S3L + fo);
    acc3 = MFMA16(a3h[k3], bh, acc3, 0, 0, 0);
    acc3 = MFMA16(a3l[k3], bh, acc3, 0, 0, 0);
    acc3 = MFMA16(a3h[k3], bl, acc3, 0, 0, 0);
  }
  const float bias3 = sb3[m];
#pragma unroll
  for (int reg = 0; reg < 4; ++reg){
    const int R = rowBase + quad * 4 + reg;
    if (R < 1022) out[R * 16 + m] = acc3[reg] + bias3;
  }
}

// ------------- MFMA fused conv1(pad2)+gelu+conv2+len-scale -----------------
// 16x16 out tile per block (grid 32x32x2), 256 threads = 4 waves.
// S-tile (20x20x16) and gelu-tile (18x18x16/chunk) held in LDS as bf16 hi/lo;
// A-fragments are direct ds_read_b128 (tap-major K-order); conv weights
// pre-packed to B-fragment hi/lo with K padded to 160 (tap 9 = zeros).
// 3 oc-chunks of 16: GEMM1(N=16) -> gelu -> h-LDS -> GEMM2 partial-K.
__global__ __launch_bounds__(256) void conv_mfma(
    const float* __restrict__ Sd, const short* __restrict__ pk,
    const float* __restrict__ cb1, const float* __restrict__ cb2,
    float* __restrict__ out)
{
  // sT: 400 pixels, stride 24 shorts (bank-friendly 48B), ic 0..15
  __shared__ __attribute__((aligned(16))) short sH[9600];
  __shared__ __attribute__((aligned(16))) short sL[9600];
  // h: 324 pixels (18x18), stride 16 shorts, current chunk's 16 channels
  __shared__ __attribute__((aligned(16))) short hH[5184];
  __shared__ __attribute__((aligned(16))) short hL[5184];
  // total 59136 B < 64K static limit; 2 blocks/CU

  const int tid = threadIdx.x;
  const int X0 = blockIdx.x * 16, Y0 = blockIdx.y * 16, bb = blockIdx.z;
  const int lane = tid & 63, wave = tid >> 6;
  const int mcol = lane & 15, quad = lane >> 4;
  const int tq = quad >> 1, icl0 = (quad & 1) * 8;

  // ---- stage S tile (halo 2, zero-padded), convert to bf16 hi/lo ----
  for (int e = tid; e < 1600; e += 256){
    const int q = e & 3, p = e >> 2;
    const int row = p / 20, col = p % 20;
    const int gy = Y0 - 2 + row, gx = X0 - 2 + col;
    float4 v = make_float4(0.f, 0.f, 0.f, 0.f);
    if (gy >= 0 && gy < 512 && gx >= 0 && gx < 512)
      v = *(const float4*)(Sd + (((gy * 512 + gx) * 2 + bb) * 16 + q * 4));
    float f[4] = {v.x, v.y, v.z, v.w};
    s4v h4, l4;
#pragma unroll
    for (int t = 0; t < 4; ++t){
      unsigned short h = f2bf(f[t]);
      h4[t] = (short)h;
      l4[t] = (short)f2bf(f[t] - bf2f(h));
    }
    *(s4v*)&sH[p * 24 + q * 4] = h4;
    *(s4v*)&sL[p * 24 + q * 4] = l4;
  }
  __syncthreads();

  // GEMM1 A-row bases (24 m-tiles of 16 over 324 pixels, 6 per wave)
  int base1[6];
#pragma unroll
  for (int it = 0; it < 6; ++it){
    int p = (wave * 6 + it) * 16 + mcol; if (p > 323) p = 323;
    const int u = p / 18, v = p - u * 18;
    base1[it] = (u * 20 + v) * 24 + icl0;
  }
  // GEMM2 A-row bases (16 m-tiles over 16x16 pixels, 4 per wave)
  int base2[4];
#pragma unroll
  for (int t2 = 0; t2 < 4; ++t2){
    const int p = (wave * 4 + t2) * 16 + mcol;
    base2[t2] = (p >> 4) * 18 + (p & 15);
  }

  const float bias2 = cb2[mcol];
  f4v acc2[4];
#pragma unroll
  for (int t2 = 0; t2 < 4; ++t2) acc2[t2] = (f4v){0.f,0.f,0.f,0.f};

  for (int chunk = 0; chunk < 3; ++chunk){
    // ---- GEMM1: this chunk's 16 output channels ----
    f4v c1[6];
#pragma unroll
    for (int it = 0; it < 6; ++it) c1[it] = (f4v){0.f,0.f,0.f,0.f};
    for (int ks = 0; ks < 5; ++ks){
      int tap = ks * 2 + tq; if (tap > 8) tap = 8;   // tap9 -> B is zero
      const int ky = tap / 3, kx = tap - ky * 3;
      const int off1 = (ky * 20 + kx) * 24;
      const int fo = ((chunk * 5 + ks) * 64 + lane) << 3;
      const s8v b1h = *(const s8v*)(pk + C1H + fo);
      const s8v b1l = *(const s8v*)(pk + C1L + fo);
#pragma unroll
      for (int it = 0; it < 6; ++it){
        const int a = base1[it] + off1;
        const s8v ah = *(const s8v*)&sH[a];
        const s8v al = *(const s8v*)&sL[a];
        c1[it] = MFMA16(ah, b1h, c1[it], 0, 0, 0);
        c1[it] = MFMA16(al, b1h, c1[it], 0, 0, 0);
        c1[it] = MFMA16(ah, b1l, c1[it], 0, 0, 0);
      }
    }
    // ---- epilogue1: bias + gelu -> h LDS (hi/lo) ----
    const float bias1 = cb1[chunk * 16 + mcol];
#pragma unroll
    for (int it = 0; it < 6; ++it){
      const int pb = (wave * 6 + it) * 16 + quad * 4;
#pragma unroll
      for (int reg = 0; reg < 4; ++reg){
        const int p = pb + reg;
        if (p < 324){
          const float v = gelu_f(c1[it][reg] + bias1);
          const unsigned short h = f2bf(v);
          hH[p * 16 + mcol] = (short)h;
          hL[p * 16 + mcol] = (short)f2bf(v - bf2f(h));
        }
      }
    }
    __syncthreads();
    // ---- GEMM2 partial K (this chunk's 16 input channels) ----
    for (int ks = 0; ks < 5; ++ks){
      int tap = ks * 2 + tq; if (tap > 8) tap = 8;
      const int ky = tap / 3, kx = tap - ky * 3;
      const int off2 = ky * 18 + kx;
      const int fo = ((chunk * 5 + ks) * 64 + lane) << 3;
      const s8v b2h = *(const s8v*)(pk + C2H + fo);
      const s8v b2l = *(const s8v*)(pk + C2L + fo);
#pragma unroll
      for (int t2 = 0; t2 < 4; ++t2){
        const int a = (base2[t2] + off2) * 16 + icl0;
        const s8v ah = *(const s8v*)&hH[a];
        const s8v al = *(const s8v*)&hL[a];
        acc2[t2] = MFMA16(ah, b2h, acc2[t2], 0, 0, 0);
        acc2[t2] = MFMA16(al, b2h, acc2[t2], 0, 0, 0);
        acc2[t2] = MFMA16(ah, b2l, acc2[t2], 0, 0, 0);
      }
    }
    __syncthreads();   // before next chunk overwrites h
  }
  // ---- epilogue2: bias + length-scale + store ----
#pragma unroll
  for (int t2 = 0; t2 < 4; ++t2){
#pragma unroll
    for (int reg = 0; reg < 4; ++reg){
      const int p = (wave * 4 + t2) * 16 + quad * 4 + reg;
      const int Y = Y0 + (p >> 4), X = X0 + (p & 15);
      int l = Y - X; if (l < 0) l = -l; if (l < 1) l = 1;
      out[((Y * 512 + X) * 2 + bb) * 16 + mcol] = (acc2[t2][reg] + bias2) * (float)l;
    }
  }
}

// ---------------------------------------------------------------------------
extern "C" void kernel_launch(void* const* d_in, const int* in_sizes, int n_in,
                              void* d_out, int out_size, void* d_ws, size_t ws_size,
                              hipStream_t stream)
{
  (void)in_sizes; (void)n_in; (void)out_size; (void)ws_size;
  const float* x   = (const float*)d_in[0];
  const float* w1  = (const float*)d_in[1];
  const float* b1  = (const float*)d_in[2];
  const float* w2  = (const float*)d_in[3];
  const float* b2  = (const float*)d_in[4];
  const float* w3  = (const float*)d_in[5];
  const float* b3  = (const float*)d_in[6];
  const float* sw1 = (const float*)d_in[7];
  const float* sb1 = (const float*)d_in[8];
  const float* sw2 = (const float*)d_in[9];
  const float* sb2 = (const float*)d_in[10];
  const float* sw3 = (const float*)d_in[11];
  const float* sb3 = (const float*)d_in[12];
  const float* cw1 = (const float*)d_in[13];
  const float* cb1 = (const float*)d_in[14];
  const float* cw2 = (const float*)d_in[15];
  const float* cb2 = (const float*)d_in[16];

  float* ws  = (float*)d_ws;
  float* xc  = ws;
  float* x2c = ws + 131328;
  float* x3c = ws + 262656;
  float* Sd  = ws + 393984;
  short* pk  = (short*)(ws + 8782592);
  float* outS = (float*)d_out;
  float* outK = outS + 8388608;

  prefix_k<<<3, 256, 0, stream>>>(x, xc, x2c, x3c);
  pack_w<<<192, 256, 0, stream>>>(w1, 768, 24, 49152, pk + W1H, pk + W1L);
  pack_w<<<16,  256, 0, stream>>>(w2,  64,  2,  4096, pk + W2H, pk + W2L);
  pack_w<<<4,   256, 0, stream>>>(w3,  64,  2,  1024, pk + W3H, pk + W3L);
  pack_w<<<96,  256, 0, stream>>>(sw1, 384, 12, 24576, pk + S1H, pk + S1L);
  pack_w<<<16,  256, 0, stream>>>(sw2, 64,  2,  4096, pk + S2H, pk + S2L);
  pack_w<<<4,   256, 0, stream>>>(sw3, 64,  2,  1024, pk + S3H, pk + S3L);
  pack_c1<<<30, 256, 0, stream>>>(cw1, pk + C1H, pk + C1L);
  pack_c2<<<30, 256, 0, stream>>>(cw2, pk + C2H, pk + C2L);
  hipMemsetAsync(Sd, 0, (size_t)8388608 * 4, stream);
  pair_mlp<<<1026, 512, 0, stream>>>(x, xc, x2c, x3c, pk, b1, b2, b3, Sd);
  skip_mlp<<<16, 256, 0, stream>>>(x, pk, sb1, sb2, sb3, outK);
  conv_mfma<<<dim3(32, 32, 2), 256, 0, stream>>>(Sd, pk, cb1, cb2, outS);
}

// Round 4
// 498.254 us; speedup vs baseline: 1.4881x; 1.1874x over previous
//
#include <hip/hip_runtime.h>
#include <math.h>

// ---------------------------------------------------------------------------
// PairwiseFeatureBatch: N=512, B=2, D=128, O=16, H=64, CH=48
//   out0: S [512,512,2,16] f32 ; out1: S_skip [511,2,16] f32
// ws (floats): xc@0 x2c@131328 x3c@262656 Sd@393984 pk@8782592(short area)
// 3 dispatches: setup_fused -> pair_mlp(+skip blocks) -> conv_mfma
// ---------------------------------------------------------------------------

typedef __attribute__((ext_vector_type(8))) short s8v;
typedef __attribute__((ext_vector_type(4))) float f4v;

union U8 { int i[4]; s8v s; };

__device__ __forceinline__ unsigned short f2bf(float f){
  unsigned u = __float_as_uint(f);
  unsigned r = u + 0x7FFFu + ((u >> 16) & 1u);
  return (unsigned short)(r >> 16);
}
__device__ __forceinline__ float bf2f(unsigned short h){
  return __uint_as_float(((unsigned)h) << 16);
}
__device__ __forceinline__ float gelu_f(float v){
  return 0.5f * v * (1.0f + erff(v * 0.7071067811865476f));
}
__device__ __forceinline__ int inv_tri(int p){
  float t = sqrtf(8.0f * (float)p + 1.0f);
  int i = (int)((t - 1.0f) * 0.5f);
  while ((i + 1) * (i + 2) / 2 <= p) ++i;
  while (i * (i + 1) / 2 > p) --i;
  return i;
}
// truncation hi/lo split, v_perm packing (hi exact-residual: lo = f - hi)
__device__ __forceinline__ void cvt8(const float v[8], s8v& hi, s8v& lo){
  U8 H, L;
#pragma unroll
  for (int t = 0; t < 4; ++t){
    const unsigned a = __float_as_uint(v[2*t]);
    const unsigned b = __float_as_uint(v[2*t+1]);
    H.i[t] = (int)__builtin_amdgcn_perm(b, a, 0x07060302u);
    const float la = v[2*t]   - __uint_as_float(a & 0xFFFF0000u);
    const float lb = v[2*t+1] - __uint_as_float(b & 0xFFFF0000u);
    L.i[t] = (int)__builtin_amdgcn_perm(__float_as_uint(lb), __float_as_uint(la), 0x07060302u);
  }
  hi = H.s; lo = L.s;
}
__device__ __forceinline__ void ld8(const float* p, float v[8]){
  const float4 a0 = *(const float4*)p;
  const float4 a1 = *(const float4*)(p + 4);
  v[0]=a0.x; v[1]=a0.y; v[2]=a0.z; v[3]=a0.w;
  v[4]=a1.x; v[5]=a1.y; v[6]=a1.z; v[7]=a1.w;
}

// packed-area short offsets
#define W1H 0
#define W1L 49152
#define W2H 98304
#define W2L 102400
#define W3H 106496
#define W3L 107520
#define S1H 108544
#define S1L 133120
#define S2H 157696
#define S2L 161792
#define S3H 165888
#define S3L 166912
#define C1H 167936
#define C1L 175616
#define C2H 183296
#define C2L 190976

#define MFMA16 __builtin_amdgcn_mfma_f32_16x16x32_bf16

// ----------------------- fused setup (packs + prefix) ----------------------
__device__ __forceinline__ void pw_dev(const float* __restrict__ W,
    int K, int KS, int nEl, short* __restrict__ hiD, short* __restrict__ loD, int pos)
{
  if (pos >= nEl) return;
  const int j = pos & 7, lane = (pos >> 3) & 63, t2 = pos >> 9;
  const int ks = t2 % KS, nt = t2 / KS;
  const int n = nt * 16 + (lane & 15);
  const int k = ks * 32 + ((lane >> 4) & 3) * 8 + j;
  const float v = W[n * K + k];
  const unsigned short h = f2bf(v);
  hiD[pos] = (short)h;
  loD[pos] = (short)f2bf(v - bf2f(h));
}
__device__ __forceinline__ void pc1_dev(const float* __restrict__ W,
    short* __restrict__ hiD, short* __restrict__ loD, int pos)
{
  if (pos >= 7680) return;
  const int j = pos & 7, lane = (pos >> 3) & 63, t2 = pos >> 9;
  const int ks = t2 % 5, chunk = t2 / 5;
  const int n = chunk * 16 + (lane & 15);
  const int k = ks * 32 + ((lane >> 4) & 3) * 8 + j;
  const int tap = k >> 4, ic = k & 15;
  const float v = (tap < 9) ? W[(n * 16 + ic) * 9 + tap] : 0.0f;
  const unsigned short h = f2bf(v);
  hiD[pos] = (short)h;
  loD[pos] = (short)f2bf(v - bf2f(h));
}
__device__ __forceinline__ void pc2_dev(const float* __restrict__ W,
    short* __restrict__ hiD, short* __restrict__ loD, int pos)
{
  if (pos >= 7680) return;
  const int j = pos & 7, lane = (pos >> 3) & 63, t2 = pos >> 9;
  const int ks = t2 % 5, chunk = t2 / 5;
  const int n = lane & 15;
  const int k = ks * 32 + ((lane >> 4) & 3) * 8 + j;
  const int tap = k >> 4, ic = chunk * 16 + (k & 15);
  const float v = (tap < 9) ? W[(n * 48 + ic) * 9 + tap] : 0.0f;
  const unsigned short h = f2bf(v);
  hiD[pos] = (short)h;
  loD[pos] = (short)f2bf(v - bf2f(h));
}

__global__ __launch_bounds__(256) void setup_fused(
    const float* __restrict__ x,
    const float* __restrict__ w1, const float* __restrict__ w2,
    const float* __restrict__ w3, const float* __restrict__ sw1,
    const float* __restrict__ sw2, const float* __restrict__ sw3,
    const float* __restrict__ cw1, const float* __restrict__ cw2,
    float* __restrict__ xc, float* __restrict__ x2c, float* __restrict__ x3c,
    short* __restrict__ pk)
{
  const int b = blockIdx.x, tid = threadIdx.x;
  if (b < 192)      pw_dev(w1, 768, 24, 49152, pk + W1H, pk + W1L, b * 256 + tid);
  else if (b < 208) pw_dev(w2,  64,  2,  4096, pk + W2H, pk + W2L, (b-192) * 256 + tid);
  else if (b < 212) pw_dev(w3,  64,  2,  1024, pk + W3H, pk + W3L, (b-208) * 256 + tid);
  else if (b < 308) pw_dev(sw1,384, 12, 24576, pk + S1H, pk + S1L, (b-212) * 256 + tid);
  else if (b < 324) pw_dev(sw2, 64,  2,  4096, pk + S2H, pk + S2L, (b-308) * 256 + tid);
  else if (b < 328) pw_dev(sw3, 64,  2,  1024, pk + S3H, pk + S3L, (b-324) * 256 + tid);
  else if (b < 358) pc1_dev(cw1, pk + C1H, pk + C1L, (b-328) * 256 + tid);
  else if (b < 388) pc2_dev(cw2, pk + C2H, pk + C2L, (b-358) * 256 + tid);
  else {
    const int mom = b - 388;
    float* dst = (mom == 0) ? xc : ((mom == 1) ? x2c : x3c);
    float acc = 0.0f;
    dst[tid] = 0.0f;
#pragma unroll 8
    for (int n = 0; n < 512; ++n){
      float v = x[n * 256 + tid];
      if (mom == 1) v = v * v;
      else if (mom == 2) v = v * v * v;
      acc += v;
      dst[(n + 1) * 256 + tid] = acc;
    }
  }
}

// ---------------- pairwise MLP (blocks 0..2051) + skip (2052..2067) --------
// 256 threads = 4 waves; pair: 32 rows/wave; LDS 32KB -> up to 5 blocks/CU.
// LDS epilogue layout XOR-swizzled: col ^= ((row>>2)&3)<<4  (conflict-free
// stores; reads stay b128-contiguous).
__global__ __launch_bounds__(256) void pair_mlp(
    const float* __restrict__ x, const float* __restrict__ xc,
    const float* __restrict__ x2c, const float* __restrict__ x3c,
    const short* __restrict__ pk,
    const float* __restrict__ b1, const float* __restrict__ b2,
    const float* __restrict__ b3,
    const float* __restrict__ sb1, const float* __restrict__ sb2,
    const float* __restrict__ sb3,
    float* __restrict__ Sd, float* __restrict__ outK)
{
  __shared__ __attribute__((aligned(16))) short hh[4][2048];
  __shared__ __attribute__((aligned(16))) short hl[4][2048];
  const int tid = threadIdx.x;
  const int wave = tid >> 6, lane = tid & 63;
  const int m = lane & 15, quad = lane >> 4;

  if (blockIdx.x >= 2052){
    // ------------------------- skip MLP path -------------------------------
    const int rowBase = (blockIdx.x - 2052) * 64 + wave * 16;
    int r = rowBase + m; if (r > 1021) r = 1021;
    const int nidx = r >> 1, bb = r & 1;
    const int oi = (nidx * 2 + bb) * 128, oj = ((nidx + 1) * 2 + bb) * 128;

    f4v acc[4];
#pragma unroll
    for (int nt = 0; nt < 4; ++nt) acc[nt] = (f4v){0.f,0.f,0.f,0.f};

    for (int d4 = 0; d4 < 4; ++d4){
      const int d0 = d4 * 32 + quad * 8;
      float vi[8], vj[8], vp[8];
      ld8(x + oi + d0, vi); ld8(x + oj + d0, vj);
#pragma unroll
      for (int t = 0; t < 8; ++t) vp[t] = vi[t] * vj[t];
      s8v ah[3], al[3];
      cvt8(vi, ah[0], al[0]); cvt8(vj, ah[1], al[1]); cvt8(vp, ah[2], al[2]);
#pragma unroll
      for (int c = 0; c < 3; ++c){
        const int ks = c * 4 + d4;
#pragma unroll
        for (int nt = 0; nt < 4; ++nt){
          const int fo = ((nt * 12 + ks) * 64 + lane) << 3;
          const s8v bh = *(const s8v*)(pk + S1H + fo);
          const s8v bl = *(const s8v*)(pk + S1L + fo);
          acc[nt] = MFMA16(ah[c], bh, acc[nt], 0, 0, 0);
          acc[nt] = MFMA16(al[c], bh, acc[nt], 0, 0, 0);
          acc[nt] = MFMA16(ah[c], bl, acc[nt], 0, 0, 0);
        }
      }
    }
#pragma unroll
    for (int nt = 0; nt < 4; ++nt){
      const float bias = sb1[nt * 16 + m];
#pragma unroll
      for (int reg = 0; reg < 4; ++reg){
        const float v = gelu_f(acc[nt][reg] + bias);
        const int idx = (quad * 4 + reg) * 64 + ((nt * 16 + m) ^ (quad << 4));
        const unsigned uv = __float_as_uint(v);
        hh[wave][idx] = (short)(uv >> 16);
        const float lo = v - __uint_as_float(uv & 0xFFFF0000u);
        hl[wave][idx] = (short)(__float_as_uint(lo) >> 16);
      }
    }
    __syncthreads();
    s8v a2h[2], a2l[2];
#pragma unroll
    for (int k2 = 0; k2 < 2; ++k2){
      const int off = m * 64 + ((k2 * 32 + quad * 8) ^ ((m >> 2) << 4));
      a2h[k2] = *(const s8v*)&hh[wave][off];
      a2l[k2] = *(const s8v*)&hl[wave][off];
    }
    __syncthreads();
    f4v acc2[4];
#pragma unroll
    for (int nt = 0; nt < 4; ++nt) acc2[nt] = (f4v){0.f,0.f,0.f,0.f};
#pragma unroll
    for (int k2 = 0; k2 < 2; ++k2)
#pragma unroll
      for (int nt = 0; nt < 4; ++nt){
        const int fo = ((nt * 2 + k2) * 64 + lane) << 3;
        const s8v bh = *(const s8v*)(pk + S2H + fo);
        const s8v bl = *(const s8v*)(pk + S2L + fo);
        acc2[nt] = MFMA16(a2h[k2], bh, acc2[nt], 0, 0, 0);
        acc2[nt] = MFMA16(a2l[k2], bh, acc2[nt], 0, 0, 0);
        acc2[nt] = MFMA16(a2h[k2], bl, acc2[nt], 0, 0, 0);
      }
#pragma unroll
    for (int nt = 0; nt < 4; ++nt){
      const float bias = sb2[nt * 16 + m];
#pragma unroll
      for (int reg = 0; reg < 4; ++reg){
        const float v = gelu_f(acc2[nt][reg] + bias);
        const int idx = (quad * 4 + reg) * 64 + ((nt * 16 + m) ^ (quad << 4));
        const unsigned uv = __float_as_uint(v);
        hh[wave][idx] = (short)(uv >> 16);
        const float lo = v - __uint_as_float(uv & 0xFFFF0000u);
        hl[wave][idx] = (short)(__float_as_uint(lo) >> 16);
      }
    }
    __syncthreads();
    s8v a3h[2], a3l[2];
#pragma unroll
    for (int k3 = 0; k3 < 2; ++k3){
      const int off = m * 64 + ((k3 * 32 + quad * 8) ^ ((m >> 2) << 4));
      a3h[k3] = *(const s8v*)&hh[wave][off];
      a3l[k3] = *(const s8v*)&hl[wave][off];
    }
    f4v acc3 = (f4v){0.f,0.f,0.f,0.f};
#pragma unroll
    for (int k3 = 0; k3 < 2; ++k3){
      const int fo = (k3 * 64 + lane) << 3;
      const s8v bh = *(const s8v*)(pk + S3H + fo);
      const s8v bl = *(const s8v*)(pk + S3L + fo);
      acc3 = MFMA16(a3h[k3], bh, acc3, 0, 0, 0);
      acc3 = MFMA16(a3l[k3], bh, acc3, 0, 0, 0);
      acc3 = MFMA16(a3h[k3], bl, acc3, 0, 0, 0);
    }
    const float bias3 = sb3[m];
#pragma unroll
    for (int reg = 0; reg < 4; ++reg){
      const int R = rowBase + quad * 4 + reg;
      if (R < 1022) outK[R * 16 + m] = acc3[reg] + bias3;
    }
    return;
  }

  // --------------------------- pair path -----------------------------------
  const int rowBase = blockIdx.x * 128 + wave * 32;
  int oi[2], oj[2], ca[2], cb[2];
  float invL[2];
#pragma unroll
  for (int s = 0; s < 2; ++s){
    const int r = rowBase + s * 16 + m;
    const int p = r >> 1, b = r & 1;
    const int i = inv_tri(p), j = p - i * (i + 1) / 2;
    oi[s] = (i * 2 + b) * 128;
    oj[s] = (j * 2 + b) * 128;
    ca[s] = (i + 1) * 256 + b * 128;
    cb[s] = j * 256 + b * 128;
    invL[s] = 1.0f / (float)(i - j + 1);
  }

  f4v acc[2][4];
#pragma unroll
  for (int s = 0; s < 2; ++s)
#pragma unroll
    for (int nt = 0; nt < 4; ++nt) acc[s][nt] = (f4v){0.f,0.f,0.f,0.f};

  // layer 1, chunks 0-2 (x_i, x_j, x_i*x_j): one load pair per d-slice
  for (int d4 = 0; d4 < 4; ++d4){
    const int d0 = d4 * 32 + quad * 8;
    s8v ah[3][2], al[3][2];
#pragma unroll
    for (int s = 0; s < 2; ++s){
      float vi[8], vj[8], vp[8];
      ld8(x + oi[s] + d0, vi); ld8(x + oj[s] + d0, vj);
#pragma unroll
      for (int t = 0; t < 8; ++t) vp[t] = vi[t] * vj[t];
      cvt8(vi, ah[0][s], al[0][s]);
      cvt8(vj, ah[1][s], al[1][s]);
      cvt8(vp, ah[2][s], al[2][s]);
    }
#pragma unroll
    for (int c = 0; c < 3; ++c){
      const int ks = c * 4 + d4;
#pragma unroll
      for (int nt = 0; nt < 4; ++nt){
        const int fo = ((nt * 24 + ks) * 64 + lane) << 3;
        const s8v bh = *(const s8v*)(pk + W1H + fo);
        const s8v bl = *(const s8v*)(pk + W1L + fo);
#pragma unroll
        for (int s = 0; s < 2; ++s){
          acc[s][nt] = MFMA16(ah[c][s], bh, acc[s][nt], 0, 0, 0);
          acc[s][nt] = MFMA16(al[c][s], bh, acc[s][nt], 0, 0, 0);
          acc[s][nt] = MFMA16(ah[c][s], bl, acc[s][nt], 0, 0, 0);
        }
      }
    }
  }
  // layer 1, chunks 3-5 (moments)
  for (int ks = 12; ks < 24; ++ks){
    const int chunk = ks >> 2;
    const int d0 = (ks & 3) * 32 + quad * 8;
    const float* pa = (chunk == 3) ? xc : ((chunk == 4) ? x2c : x3c);
    s8v ahi[2], alo[2];
#pragma unroll
    for (int s = 0; s < 2; ++s){
      float a[8], bb[8], v[8];
      ld8(pa + ca[s] + d0, a); ld8(pa + cb[s] + d0, bb);
#pragma unroll
      for (int t = 0; t < 8; ++t) v[t] = (a[t] - bb[t]) * invL[s];
      cvt8(v, ahi[s], alo[s]);
    }
#pragma unroll
    for (int nt = 0; nt < 4; ++nt){
      const int fo = ((nt * 24 + ks) * 64 + lane) << 3;
      const s8v bh = *(const s8v*)(pk + W1H + fo);
      const s8v bl = *(const s8v*)(pk + W1L + fo);
#pragma unroll
      for (int s = 0; s < 2; ++s){
        acc[s][nt] = MFMA16(ahi[s], bh, acc[s][nt], 0, 0, 0);
        acc[s][nt] = MFMA16(alo[s], bh, acc[s][nt], 0, 0, 0);
        acc[s][nt] = MFMA16(ahi[s], bl, acc[s][nt], 0, 0, 0);
      }
    }
  }
  // epilogue 1 -> LDS (swizzled, truncation split)
#pragma unroll
  for (int s = 0; s < 2; ++s)
#pragma unroll
    for (int nt = 0; nt < 4; ++nt){
      const float bias = b1[nt * 16 + m];
#pragma unroll
      for (int reg = 0; reg < 4; ++reg){
        const float v = gelu_f(acc[s][nt][reg] + bias);
        const int idx = (s * 16 + quad * 4 + reg) * 64 + ((nt * 16 + m) ^ (quad << 4));
        const unsigned uv = __float_as_uint(v);
        hh[wave][idx] = (short)(uv >> 16);
        const float lo = v - __uint_as_float(uv & 0xFFFF0000u);
        hl[wave][idx] = (short)(__float_as_uint(lo) >> 16);
      }
    }
  __syncthreads();
  s8v a2h[2][2], a2l[2][2];
#pragma unroll
  for (int s = 0; s < 2; ++s)
#pragma unroll
    for (int k2 = 0; k2 < 2; ++k2){
      const int off = (s * 16 + m) * 64 + ((k2 * 32 + quad * 8) ^ ((m >> 2) << 4));
      a2h[s][k2] = *(const s8v*)&hh[wave][off];
      a2l[s][k2] = *(const s8v*)&hl[wave][off];
    }
  __syncthreads();
  // layer 2
  f4v acc2[2][4];
#pragma unroll
  for (int s = 0; s < 2; ++s)
#pragma unroll
    for (int nt = 0; nt < 4; ++nt) acc2[s][nt] = (f4v){0.f,0.f,0.f,0.f};
#pragma unroll
  for (int k2 = 0; k2 < 2; ++k2)
#pragma unroll
    for (int nt = 0; nt < 4; ++nt){
      const int fo = ((nt * 2 + k2) * 64 + lane) << 3;
      const s8v bh = *(const s8v*)(pk + W2H + fo);
      const s8v bl = *(const s8v*)(pk + W2L + fo);
#pragma unroll
      for (int s = 0; s < 2; ++s){
        acc2[s][nt] = MFMA16(a2h[s][k2], bh, acc2[s][nt], 0, 0, 0);
        acc2[s][nt] = MFMA16(a2l[s][k2], bh, acc2[s][nt], 0, 0, 0);
        acc2[s][nt] = MFMA16(a2h[s][k2], bl, acc2[s][nt], 0, 0, 0);
      }
    }
#pragma unroll
  for (int s = 0; s < 2; ++s)
#pragma unroll
    for (int nt = 0; nt < 4; ++nt){
      const float bias = b2[nt * 16 + m];
#pragma unroll
      for (int reg = 0; reg < 4; ++reg){
        const float v = gelu_f(acc2[s][nt][reg] + bias);
        const int idx = (s * 16 + quad * 4 + reg) * 64 + ((nt * 16 + m) ^ (quad << 4));
        const unsigned uv = __float_as_uint(v);
        hh[wave][idx] = (short)(uv >> 16);
        const float lo = v - __uint_as_float(uv & 0xFFFF0000u);
        hl[wave][idx] = (short)(__float_as_uint(lo) >> 16);
      }
    }
  __syncthreads();
  s8v a3h[2][2], a3l[2][2];
#pragma unroll
  for (int s = 0; s < 2; ++s)
#pragma unroll
    for (int k3 = 0; k3 < 2; ++k3){
      const int off = (s * 16 + m) * 64 + ((k3 * 32 + quad * 8) ^ ((m >> 2) << 4));
      a3h[s][k3] = *(const s8v*)&hh[wave][off];
      a3l[s][k3] = *(const s8v*)&hl[wave][off];
    }
  // layer 3
  f4v acc3[2];
  acc3[0] = (f4v){0.f,0.f,0.f,0.f};
  acc3[1] = (f4v){0.f,0.f,0.f,0.f};
#pragma unroll
  for (int k3 = 0; k3 < 2; ++k3){
    const int fo = (k3 * 64 + lane) << 3;
    const s8v bh = *(const s8v*)(pk + W3H + fo);
    const s8v bl = *(const s8v*)(pk + W3L + fo);
#pragma unroll
    for (int s = 0; s < 2; ++s){
      acc3[s] = MFMA16(a3h[s][k3], bh, acc3[s], 0, 0, 0);
      acc3[s] = MFMA16(a3l[s][k3], bh, acc3[s], 0, 0, 0);
      acc3[s] = MFMA16(a3h[s][k3], bl, acc3[s], 0, 0, 0);
    }
  }
  const float bias3 = b3[m];
#pragma unroll
  for (int s = 0; s < 2; ++s)
#pragma unroll
    for (int reg = 0; reg < 4; ++reg){
      const int R = rowBase + s * 16 + quad * 4 + reg;
      const int p = R >> 1, bb = R & 1;
      const int i = inv_tri(p), j = p - i * (i + 1) / 2;
      Sd[((i * 512 + j) * 2 + bb) * 16 + m] = acc3[s][reg] + bias3;
    }
}

// ------------- MFMA fused conv1(pad2)+gelu+conv2+len-scale -----------------
// tril-aware staging (upper triangle of Sd never written -> read as 0).
__global__ __launch_bounds__(256) void conv_mfma(
    const float* __restrict__ Sd, const short* __restrict__ pk,
    const float* __restrict__ cb1, const float* __restrict__ cb2,
    float* __restrict__ out)
{
  __shared__ __attribute__((aligned(16))) short sH[9600];
  __shared__ __attribute__((aligned(16))) short sL[9600];
  __shared__ __attribute__((aligned(16))) short hH[5184];
  __shared__ __attribute__((aligned(16))) short hL[5184];

  const int tid = threadIdx.x;
  const int X0 = blockIdx.x * 16, Y0 = blockIdx.y * 16, bb = blockIdx.z;
  const int lane = tid & 63, wave = tid >> 6;
  const int mcol = lane & 15, quad = lane >> 4;
  const int tq = quad >> 1, icl0 = (quad & 1) * 8;

  for (int e = tid; e < 1600; e += 256){
    const int q = e & 3, p = e >> 2;
    const int row = p / 20, col = p % 20;
    const int gy = Y0 - 2 + row, gx = X0 - 2 + col;
    float4 v = make_float4(0.f, 0.f, 0.f, 0.f);
    if (gy >= 0 && gy < 512 && gx >= 0 && gx <= gy)
      v = *(const float4*)(Sd + (((gy * 512 + gx) * 2 + bb) * 16 + q * 4));
    const float f[4] = {v.x, v.y, v.z, v.w};
    int h2[2], l2[2];
#pragma unroll
    for (int t = 0; t < 2; ++t){
      const unsigned a = __float_as_uint(f[2*t]);
      const unsigned b = __float_as_uint(f[2*t+1]);
      h2[t] = (int)__builtin_amdgcn_perm(b, a, 0x07060302u);
      const float la = f[2*t]   - __uint_as_float(a & 0xFFFF0000u);
      const float lb = f[2*t+1] - __uint_as_float(b & 0xFFFF0000u);
      l2[t] = (int)__builtin_amdgcn_perm(__float_as_uint(lb), __float_as_uint(la), 0x07060302u);
    }
    *(int*)&sH[p * 24 + q * 4]     = h2[0];
    *(int*)&sH[p * 24 + q * 4 + 2] = h2[1];
    *(int*)&sL[p * 24 + q * 4]     = l2[0];
    *(int*)&sL[p * 24 + q * 4 + 2] = l2[1];
  }
  __syncthreads();

  int base1[6];
#pragma unroll
  for (int it = 0; it < 6; ++it){
    int p = (wave * 6 + it) * 16 + mcol; if (p > 323) p = 323;
    const int u = p / 18, v = p - u * 18;
    base1[it] = (u * 20 + v) * 24 + icl0;
  }
  int base2[4];
#pragma unroll
  for (int t2 = 0; t2 < 4; ++t2){
    const int p = (wave * 4 + t2) * 16 + mcol;
    base2[t2] = (p >> 4) * 18 + (p & 15);
  }

  const float bias2 = cb2[mcol];
  f4v acc2[4];
#pragma unroll
  for (int t2 = 0; t2 < 4; ++t2) acc2[t2] = (f4v){0.f,0.f,0.f,0.f};

  for (int chunk = 0; chunk < 3; ++chunk){
    f4v c1[6];
#pragma unroll
    for (int it = 0; it < 6; ++it) c1[it] = (f4v){0.f,0.f,0.f,0.f};
    for (int ks = 0; ks < 5; ++ks){
      int tap = ks * 2 + tq; if (tap > 8) tap = 8;
      const int ky = tap / 3, kx = tap - ky * 3;
      const int off1 = (ky * 20 + kx) * 24;
      const int fo = ((chunk * 5 + ks) * 64 + lane) << 3;
      const s8v b1h = *(const s8v*)(pk + C1H + fo);
      const s8v b1l = *(const s8v*)(pk + C1L + fo);
#pragma unroll
      for (int it = 0; it < 6; ++it){
        const int a = base1[it] + off1;
        const s8v ah = *(const s8v*)&sH[a];
        const s8v al = *(const s8v*)&sL[a];
        c1[it] = MFMA16(ah, b1h, c1[it], 0, 0, 0);
        c1[it] = MFMA16(al, b1h, c1[it], 0, 0, 0);
        c1[it] = MFMA16(ah, b1l, c1[it], 0, 0, 0);
      }
    }
    const float bias1 = cb1[chunk * 16 + mcol];
#pragma unroll
    for (int it = 0; it < 6; ++it){
      const int pb = (wave * 6 + it) * 16 + quad * 4;
#pragma unroll
      for (int reg = 0; reg < 4; ++reg){
        const int p = pb + reg;
        if (p < 324){
          const float v = gelu_f(c1[it][reg] + bias1);
          const unsigned uv = __float_as_uint(v);
          hH[p * 16 + mcol] = (short)(uv >> 16);
          const float lo = v - __uint_as_float(uv & 0xFFFF0000u);
          hL[p * 16 + mcol] = (short)(__float_as_uint(lo) >> 16);
        }
      }
    }
    __syncthreads();
    for (int ks = 0; ks < 5; ++ks){
      int tap = ks * 2 + tq; if (tap > 8) tap = 8;
      const int ky = tap / 3, kx = tap - ky * 3;
      const int off2 = ky * 18 + kx;
      const int fo = ((chunk * 5 + ks) * 64 + lane) << 3;
      const s8v b2h = *(const s8v*)(pk + C2H + fo);
      const s8v b2l = *(const s8v*)(pk + C2L + fo);
#pragma unroll
      for (int t2 = 0; t2 < 4; ++t2){
        const int a = (base2[t2] + off2) * 16 + icl0;
        const s8v ah = *(const s8v*)&hH[a];
        const s8v al = *(const s8v*)&hL[a];
        acc2[t2] = MFMA16(ah, b2h, acc2[t2], 0, 0, 0);
        acc2[t2] = MFMA16(al, b2h, acc2[t2], 0, 0, 0);
        acc2[t2] = MFMA16(ah, b2l, acc2[t2], 0, 0, 0);
      }
    }
    __syncthreads();
  }
#pragma unroll
  for (int t2 = 0; t2 < 4; ++t2){
#pragma unroll
    for (int reg = 0; reg < 4; ++reg){
      const int p = (wave * 4 + t2) * 16 + quad * 4 + reg;
      const int Y = Y0 + (p >> 4), X = X0 + (p & 15);
      int l = Y - X; if (l < 0) l = -l; if (l < 1) l = 1;
      out[((Y * 512 + X) * 2 + bb) * 16 + mcol] = (acc2[t2][reg] + bias2) * (float)l;
    }
  }
}

// ---------------------------------------------------------------------------
extern "C" void kernel_launch(void* const* d_in, const int* in_sizes, int n_in,
                              void* d_out, int out_size, void* d_ws, size_t ws_size,
                              hipStream_t stream)
{
  (void)in_sizes; (void)n_in; (void)out_size; (void)ws_size;
  const float* x   = (const float*)d_in[0];
  const float* w1  = (const float*)d_in[1];
  const float* b1  = (const float*)d_in[2];
  const float* w2  = (const float*)d_in[3];
  const float* b2  = (const float*)d_in[4];
  const float* w3  = (const float*)d_in[5];
  const float* b3  = (const float*)d_in[6];
  const float* sw1 = (const float*)d_in[7];
  const float* sb1 = (const float*)d_in[8];
  const float* sw2 = (const float*)d_in[9];
  const float* sb2 = (const float*)d_in[10];
  const float* sw3 = (const float*)d_in[11];
  const float* sb3 = (const float*)d_in[12];
  const float* cw1 = (const float*)d_in[13];
  const float* cb1 = (const float*)d_in[14];
  const float* cw2 = (const float*)d_in[15];
  const float* cb2 = (const float*)d_in[16];

  float* ws  = (float*)d_ws;
  float* xc  = ws;
  float* x2c = ws + 131328;
  float* x3c = ws + 262656;
  float* Sd  = ws + 393984;
  short* pk  = (short*)(ws + 8782592);
  float* outS = (float*)d_out;
  float* outK = outS + 8388608;

  setup_fused<<<391, 256, 0, stream>>>(x, w1, w2, w3, sw1, sw2, sw3, cw1, cw2,
                                       xc, x2c, x3c, pk);
  pair_mlp<<<2068, 256, 0, stream>>>(x, xc, x2c, x3c, pk, b1, b2, b3,
                                     sb1, sb2, sb3, Sd, outK);
  conv_mfma<<<dim3(32, 32, 2), 256, 0, stream>>>(Sd, pk, cb1, cb2, outS);
}